// Round 5
// baseline (59.541 us; speedup 1.0000x reference)
//
#include <hip/hip_runtime.h>

#define BATCH 4096
#define FEAT  2048
#define GRID  1024   // 4 rows per block (one per wave)

typedef float f32x4 __attribute__((ext_vector_type(4)));

// Fused: per-wave row distance -> per-block partial -> last block reduces.
// ws layout: [0..3] counter (uint, memset to 0 each call); [256..] GRID floats.
__global__ __launch_bounds__(256) void center_loss_fused(
        const float* __restrict__ x,
        const int*   __restrict__ labels,
        const float* __restrict__ centers,
        unsigned int* __restrict__ counter,
        float*       __restrict__ partials,
        float*       __restrict__ out) {
    const int wave = threadIdx.x >> 6;
    const int lane = threadIdx.x & 63;
    const int row  = (blockIdx.x << 2) | wave;

    const int lbl = labels[row];                      // wave-uniform -> scalar load
    const f32x4* __restrict__ xr = (const f32x4*)(x + (size_t)row * FEAT) + lane;
    const f32x4* __restrict__ cr = (const f32x4*)(centers + (size_t)lbl * FEAT) + lane;

    // issue all 16 loads before any arithmetic
    f32x4 xv[8], cv[8];
#pragma unroll
    for (int i = 0; i < 8; ++i)
        xv[i] = __builtin_nontemporal_load(xr + (i << 6));   // x: streamed, no reuse
#pragma unroll
    for (int i = 0; i < 8; ++i)
        cv[i] = cr[i << 6];                                   // centers: cacheable (label dups)

    float p = 0.f;
#pragma unroll
    for (int i = 0; i < 8; ++i) {
        f32x4 d = xv[i] - cv[i];
        p += d.x * d.x + d.y * d.y + d.z * d.z + d.w * d.w;
    }

#pragma unroll
    for (int off = 32; off > 0; off >>= 1)
        p += __shfl_down(p, off, 64);

    __shared__ float sw[4];
    __shared__ unsigned int slast;
    if (lane == 0)
        sw[wave] = fminf(fmaxf(p, 1e-12f), 1e12f);            // per-row clamp
    __syncthreads();

    if (threadIdx.x == 0) {
        partials[blockIdx.x] = sw[0] + sw[1] + sw[2] + sw[3];
        __threadfence();                       // release: flush partial device-wide
        slast = atomicAdd(counter, 1u);        // device-scope RMW
    }
    __syncthreads();

    if (slast == GRID - 1) {
        __threadfence();                       // acquire: invalidate stale cache
        const int t = threadIdx.x;
        const f32x4* __restrict__ pp = (const f32x4*)partials;   // 256 x f32x4
        f32x4 v = pp[t];
        float s = v.x + v.y + v.z + v.w;
#pragma unroll
        for (int off = 32; off > 0; off >>= 1)
            s += __shfl_down(s, off, 64);
        __shared__ float sw2[4];
        if ((t & 63) == 0) sw2[t >> 6] = s;
        __syncthreads();
        if (t == 0)
            out[0] = (sw2[0] + sw2[1] + sw2[2] + sw2[3]) * (1.0f / (float)BATCH);
    }
}

extern "C" void kernel_launch(void* const* d_in, const int* in_sizes, int n_in,
                              void* d_out, int out_size, void* d_ws, size_t ws_size,
                              hipStream_t stream) {
    const float* x       = (const float*)d_in[0];
    const int*   labels  = (const int*)d_in[1];
    const float* centers = (const float*)d_in[2];
    float* out = (float*)d_out;

    unsigned int* counter = (unsigned int*)d_ws;
    float* partials = (float*)((char*)d_ws + 256);   // 16B-aligned, GRID floats

    hipMemsetAsync(counter, 0, sizeof(unsigned int), stream);
    center_loss_fused<<<GRID, 256, 0, stream>>>(x, labels, centers,
                                                counter, partials, out);
}

// Round 6
// 17.630 us; speedup vs baseline: 3.3773x; 3.3773x over previous
//
#include <hip/hip_runtime.h>

#define BATCH 4096
#define FEAT  2048

typedef float f32x4 __attribute__((ext_vector_type(4)));

// kernel 1: one WAVE per batch row. 1024 blocks x 256 threads (4 waves/block).
// Per lane: 8 f32x4 of x + 8 f32x4 of c. No LDS, no __syncthreads.
// Plain (cacheable) loads everywhere: x + centers both fit in the 256 MB L3
// and stay resident across graph replays (R5 evidence: NT loads on x were the
// only remaining HBM traffic, FETCH_SIZE == sizeof(x)).
__global__ __launch_bounds__(256) void center_loss_rows(
        const float* __restrict__ x,
        const int*   __restrict__ labels,
        const float* __restrict__ centers,
        float*       __restrict__ row_dist) {
    const int wave = threadIdx.x >> 6;
    const int lane = threadIdx.x & 63;
    const int row  = (blockIdx.x << 2) | wave;

    const int lbl = labels[row];                      // wave-uniform -> scalar load
    const f32x4* __restrict__ xr = (const f32x4*)(x + (size_t)row * FEAT) + lane;
    const f32x4* __restrict__ cr = (const f32x4*)(centers + (size_t)lbl * FEAT) + lane;

    // issue all 16 loads before any arithmetic (max memory parallelism)
    f32x4 xv[8], cv[8];
#pragma unroll
    for (int i = 0; i < 8; ++i)
        xv[i] = xr[i << 6];
#pragma unroll
    for (int i = 0; i < 8; ++i)
        cv[i] = cr[i << 6];

    // dist = sum((x - c)^2)
    float p = 0.f;
#pragma unroll
    for (int i = 0; i < 8; ++i) {
        f32x4 d = xv[i] - cv[i];
        p += d.x * d.x + d.y * d.y + d.z * d.z + d.w * d.w;
    }

    // wave-64 butterfly reduce
#pragma unroll
    for (int off = 32; off > 0; off >>= 1)
        p += __shfl_down(p, off, 64);

    if (lane == 0)
        row_dist[row] = fminf(fmaxf(p, 1e-12f), 1e12f);
}

// kernel 2: single block reduces the 4096 row dists -> mean
__global__ __launch_bounds__(256) void reduce_mean_kernel(
        const float* __restrict__ row_dist,
        float*       __restrict__ out) {
    const int t = threadIdx.x;
    const f32x4* __restrict__ rd = (const f32x4*)row_dist;

    float s = 0.f;
#pragma unroll
    for (int i = 0; i < BATCH / 4 / 256; ++i) {       // 4 f32x4 per thread
        f32x4 v = rd[t + i * 256];
        s += v.x + v.y + v.z + v.w;
    }

#pragma unroll
    for (int off = 32; off > 0; off >>= 1)
        s += __shfl_down(s, off, 64);

    __shared__ float sw[4];
    if ((t & 63) == 0) sw[t >> 6] = s;
    __syncthreads();

    if (t == 0)
        out[0] = (sw[0] + sw[1] + sw[2] + sw[3]) * (1.0f / (float)BATCH);
}

extern "C" void kernel_launch(void* const* d_in, const int* in_sizes, int n_in,
                              void* d_out, int out_size, void* d_ws, size_t ws_size,
                              hipStream_t stream) {
    const float* x       = (const float*)d_in[0];
    const int*   labels  = (const int*)d_in[1];
    const float* centers = (const float*)d_in[2];
    float* out = (float*)d_out;
    float* row_dist = (float*)d_ws;   // BATCH floats = 16 KB scratch

    center_loss_rows<<<BATCH / 4, 256, 0, stream>>>(x, labels, centers, row_dist);
    reduce_mean_kernel<<<1, 256, 0, stream>>>(row_dist, out);
}

// Round 7
// 16.147 us; speedup vs baseline: 3.6874x; 1.0918x over previous
//
#include <hip/hip_runtime.h>

#define BATCH 4096
#define FEAT  2048

typedef float f32x4 __attribute__((ext_vector_type(4)));

// kernel 1: TWO waves per row (half-row each). 256-thr blocks = 4 waves = 2 rows,
// grid = BATCH/2 = 2048 blocks -> 8 blocks/CU = 32 waves/CU (was 16): doubles
// TLP to hide latency on the NT x stream + center gather.
// NT on x only (R4 vs R6 evidence: cacheable x evicts centers from L2, -1.6us).
__global__ __launch_bounds__(256) void center_loss_rows(
        const float* __restrict__ x,
        const int*   __restrict__ labels,
        const float* __restrict__ centers,
        float*       __restrict__ row_dist) {
    const int wave = threadIdx.x >> 6;     // 0..3
    const int lane = threadIdx.x & 63;
    const int row  = (blockIdx.x << 1) | (wave >> 1);
    const int half = wave & 1;

    const int lbl = labels[row];                       // wave-uniform -> scalar load
    const size_t off = (size_t)(half << 10);           // half * 1024 floats
    const f32x4* __restrict__ xr = (const f32x4*)(x + (size_t)row * FEAT + off) + lane;
    const f32x4* __restrict__ cr = (const f32x4*)(centers + (size_t)lbl * FEAT + off) + lane;

    // issue all 8 loads before any arithmetic
    f32x4 xv[4], cv[4];
#pragma unroll
    for (int i = 0; i < 4; ++i)
        xv[i] = __builtin_nontemporal_load(xr + (i << 6));   // x: streamed
#pragma unroll
    for (int i = 0; i < 4; ++i)
        cv[i] = cr[i << 6];                                   // centers: cacheable

    float p = 0.f;
#pragma unroll
    for (int i = 0; i < 4; ++i) {
        f32x4 d = xv[i] - cv[i];
        p += d.x * d.x + d.y * d.y + d.z * d.z + d.w * d.w;
    }

    // wave-64 butterfly reduce
#pragma unroll
    for (int off2 = 32; off2 > 0; off2 >>= 1)
        p += __shfl_down(p, off2, 64);

    __shared__ float sw[4];
    if (lane == 0) sw[wave] = p;
    __syncthreads();

    if (threadIdx.x < 2) {                 // t=0 -> row0, t=1 -> row1
        float d = sw[(threadIdx.x << 1)] + sw[(threadIdx.x << 1) | 1];
        row_dist[(blockIdx.x << 1) | threadIdx.x] = fminf(fmaxf(d, 1e-12f), 1e12f);
    }
}

// kernel 2: single block reduces the 4096 row dists -> mean
__global__ __launch_bounds__(256) void reduce_mean_kernel(
        const float* __restrict__ row_dist,
        float*       __restrict__ out) {
    const int t = threadIdx.x;
    const f32x4* __restrict__ rd = (const f32x4*)row_dist;

    float s = 0.f;
#pragma unroll
    for (int i = 0; i < BATCH / 4 / 256; ++i) {       // 4 f32x4 per thread
        f32x4 v = rd[t + i * 256];
        s += v.x + v.y + v.z + v.w;
    }

#pragma unroll
    for (int off = 32; off > 0; off >>= 1)
        s += __shfl_down(s, off, 64);

    __shared__ float sw[4];
    if ((t & 63) == 0) sw[t >> 6] = s;
    __syncthreads();

    if (t == 0)
        out[0] = (sw[0] + sw[1] + sw[2] + sw[3]) * (1.0f / (float)BATCH);
}

extern "C" void kernel_launch(void* const* d_in, const int* in_sizes, int n_in,
                              void* d_out, int out_size, void* d_ws, size_t ws_size,
                              hipStream_t stream) {
    const float* x       = (const float*)d_in[0];
    const int*   labels  = (const int*)d_in[1];
    const float* centers = (const float*)d_in[2];
    float* out = (float*)d_out;
    float* row_dist = (float*)d_ws;   // BATCH floats = 16 KB scratch

    center_loss_rows<<<BATCH / 2, 256, 0, stream>>>(x, labels, centers, row_dist);
    reduce_mean_kernel<<<1, 256, 0, stream>>>(row_dist, out);
}